// Round 3
// baseline (269.022 us; speedup 1.0000x reference)
//
#include <hip/hip_runtime.h>
#include <hip/hip_fp16.h>

// InstantNGP hash-grid encoding, fp32 in/out.
// N_POINTS=1048576, N_LEVELS=16, F=2. SIZES[l]=2^(l+1), OFFS[l]=2^(l+1)-2.
// Hash: h = x*(P1*P2*P3) + y*(P2*P3) + z*P3 (mod 2^32).
//
// R6 (132us): 2-pt ILP spill-free but ~neutral -> not chain-latency-bound.
// VALU audit: ~800 instrs/thread-iter == both divergent paths issuing
// (lane-level q means every wave runs LDS path AND global 64b-addr path,
// partially masked) + prep recomputed per level though levels 5..15 share
// res=512 (identical cs/frac/h000/weights; only mask/off differ).
// R7: wave-uniform q (= waveId&7): each wave takes exactly one path
// (s_cbranch skips the other), one shared prep for q>=3. Results transposed
// through 16KB XOR-swizzled LDS (conflict-free) + 2 barriers/iter so global
// float4 stores stay fully coalesced. Stage levels 0..11 (32KB fp16);
// levels 12..15 via L2 (table is 1MB, L2-resident). 48KB LDS -> 2 blocks/CU
// = 32 waves/CU guaranteed.

#define N_POINTS 1048576
#define BLOCK 1024
#define NBLOCKS 512
#define ITERS 16            // 128 points per block-iter; 512*16*128 = 1048576
#define STAGED_ROWS 8190    // levels 0..11: sum 2^(l+1) = 2^13-2
#define TBL_LDS_BYTES 32768
#define LDS_BYTES (TBL_LDS_BYTES + 128 * 8 * 16)   // +16KB transpose = 49152

__device__ __forceinline__ float2 ldsRow(const unsigned* lds, unsigned idx) {
    unsigned u = lds[idx];
    __half2 h = *(__half2*)&u;
    return __half22float2(h);
}

// Computes corner hash array (h000 + D[c]) and trilinear weights, inline.
#define PREP(FRES, HARR, WARR) \
    unsigned HARR[8]; float WARR[8]; { \
        const float csx = (px + 1.0f) * (FRES); \
        const float csy = (py + 1.0f) * (FRES); \
        const float csz = (pz + 1.0f) * (FRES); \
        const float cfx = floorf(csx), cfy = floorf(csy), cfz = floorf(csz); \
        const float tx = csx - cfx, ty = csy - cfy, tz = csz - cfz; \
        const unsigned hh = (unsigned)cfx * HA + (unsigned)cfy * HB + (unsigned)cfz * HC; \
        const float ux = 1.0f - tx, uy = 1.0f - ty, uz = 1.0f - tz; \
        WARR[0] = ux*uy*uz; WARR[1] = tx*uy*uz; WARR[2] = ux*ty*uz; WARR[3] = tx*ty*uz; \
        WARR[4] = ux*uy*tz; WARR[5] = tx*uy*tz; WARR[6] = ux*ty*tz; WARR[7] = tx*ty*tz; \
        HARR[0] = hh;           HARR[1] = hh + HA;           \
        HARR[2] = hh + HB;      HARR[3] = hh + HA + HB;      \
        HARR[4] = hh + HC;      HARR[5] = hh + HA + HC;      \
        HARR[6] = hh + HB + HC; HARR[7] = hh + HA + HB + HC; \
    }

#define GATHER_LDS(HARR, WARR, MASK, OFF, O0, O1) \
    { _Pragma("unroll") for (int c = 0; c < 8; ++c) { \
        float2 f = ldsRow(lds_tb, (OFF) + ((HARR[c]) & (MASK))); \
        (O0) += f.x * WARR[c]; (O1) += f.y * WARR[c]; } }

#define GATHER_GBL(HARR, WARR, MASK, OFF, O0, O1) \
    { _Pragma("unroll") for (int c = 0; c < 8; ++c) { \
        float2 f = tb[(OFF) + ((HARR[c]) & (MASK))]; \
        (O0) += f.x * WARR[c]; (O1) += f.y * WARR[c]; } }

__global__ __launch_bounds__(BLOCK) void ngp_encode_kernel(
    const float* __restrict__ coords,
    const float* __restrict__ table,
    float* __restrict__ out)
{
    extern __shared__ unsigned char lds_raw[];
    unsigned* lds_tb = (unsigned*)lds_raw;                       // 8190 half2 rows
    float4* lds_out  = (float4*)(lds_raw + TBL_LDS_BYTES);       // 128 pts x 8 slots

    // ---- stage levels 0..11 as fp16 (float4 = 2 rows) ----
    {
        const float4* __restrict__ t4 = (const float4*)table;
        uint2* __restrict__ l2 = (uint2*)lds_tb;
        for (int r = threadIdx.x; r < STAGED_ROWS / 2; r += BLOCK) {  // 4095
            float4 v = t4[r];
            __half2 a = __floats2half2_rn(v.x, v.y);
            __half2 b = __floats2half2_rn(v.z, v.w);
            uint2 u;
            u.x = *(unsigned*)&a;
            u.y = *(unsigned*)&b;
            l2[r] = u;
        }
    }
    __syncthreads();

    constexpr unsigned P1 = 2654435761u, P2 = 29675113u, P3 = 123456789u;
    constexpr unsigned HA = P1 * P2 * P3;
    constexpr unsigned HB = P2 * P3;
    constexpr unsigned HC = P3;

    const float2* __restrict__ tb = (const float2*)table;
    float4* __restrict__ out4 = (float4*)out;

    // Wave-uniform level-pair assignment.
    const int wv   = __builtin_amdgcn_readfirstlane((int)(threadIdx.x >> 6));
    const int q    = wv & 7;            // level pair (2q, 2q+1), uniform per wave
    const int g    = wv >> 3;           // point-group 0/1
    const int lane = threadIdx.x & 63;
    const int pl   = g * 64 + lane;     // local point 0..127

    const int l0 = 2 * q;
    const unsigned mask0 = (2u << l0) - 1u, off0 = mask0 - 1u;
    const unsigned mask1 = (4u << l0) - 1u, off1 = mask1 - 1u;

    for (int it = 0; it < ITERS; ++it) {
        const int pbase = blockIdx.x * (ITERS * 128) + it * 128;
        const int p = pbase + pl;

        const float px = coords[3 * p + 0];
        const float py = coords[3 * p + 1];
        const float pz = coords[3 * p + 2];

        float o00 = 0.0f, o01 = 0.0f, o10 = 0.0f, o11 = 0.0f;

        if (q >= 6) {
            // levels 12..15: global (L2-resident 1MB table), shared prep (res 512)
            PREP(512.0f, hc, wc)
            GATHER_GBL(hc, wc, mask0, off0, o00, o01)
            GATHER_GBL(hc, wc, mask1, off1, o10, o11)
        } else if (q >= 3) {
            // levels 6..11: LDS, shared prep (res 512)
            PREP(512.0f, hc, wc)
            GATHER_LDS(hc, wc, mask0, off0, o00, o01)
            GATHER_LDS(hc, wc, mask1, off1, o10, o11)
        } else {
            // levels 0..5: LDS, two preps (res 16<<l0, 32<<l0)
            const float fres0 = (float)(16 << l0);
            const float fres1 = (float)(32 << l0);
            {
                PREP(fres0, hA, wA)
                GATHER_LDS(hA, wA, mask0, off0, o00, o01)
            }
            {
                PREP(fres1, hB, wB)
                GATHER_LDS(hB, wB, mask1, off1, o10, o11)
            }
        }

        // ---- transpose through LDS so global stores are coalesced ----
        // XOR-swizzled slot kills the stride-128B same-bank write pattern.
        lds_out[pl * 8 + (q ^ (pl & 7))] = make_float4(o00, o01, o10, o11);
        __syncthreads();
        {
            const int j = threadIdx.x;
            const int lp = j >> 3, qq = j & 7;
            float4 v = lds_out[lp * 8 + (qq ^ (lp & 7))];
            out4[(size_t)pbase * 8 + j] = v;   // 16KB contiguous per block-iter
        }
        __syncthreads();
    }
}

extern "C" void kernel_launch(void* const* d_in, const int* in_sizes, int n_in,
                              void* d_out, int out_size, void* d_ws, size_t ws_size,
                              hipStream_t stream) {
    const float* coords = (const float*)d_in[0];
    const float* table  = (const float*)d_in[1];
    float* out = (float*)d_out;

    hipFuncSetAttribute((const void*)ngp_encode_kernel,
                        hipFuncAttributeMaxDynamicSharedMemorySize,
                        LDS_BYTES);

    ngp_encode_kernel<<<NBLOCKS, BLOCK, LDS_BYTES, stream>>>(coords, table, out);
}

// Round 4
// 226.238 us; speedup vs baseline: 1.1891x; 1.1891x over previous
//
#include <hip/hip_runtime.h>
#include <hip/hip_fp16.h>

// InstantNGP hash-grid encoding, fp32 in/out.
// N_POINTS=1048576, N_LEVELS=16, F=2. SIZES[l]=2^(l+1), OFFS[l]=2^(l+1)-2.
// Hash: h = x*(P1*P2*P3) + y*(P2*P3) + z*P3 (mod 2^32).
//
// R6 (132us): lane-level q, both divergent paths issue -> VALU 34%.
// R7 (171us): wave-uniform q worked on its own terms (VALU 17.6%, conflicts
// /4.6) but regressed overall: ALL global gathers on waves q=6,7 + 2
// barriers/iter -> per-iter cost = max(wave work); plus level 12 moved to
// global (+33% scattered-gather traffic).
// R8: keep wave-uniform, fix balance: wave q handles levels (q, 15-q) so
// each wave = one cheap + one expensive level; global levels 13..15 pair
// with broadcast-cheap levels 2,1,0. Level 12 back in 64KB fp16 LDS stage
// (R4-proven). Transpose buffer now [16 levels][128 pts] float2 with XOR
// swizzle pl^(l&14): writes permuted-contiguous (BW-optimal), reads 4
// lanes/bank-pair (optimal). 80KB LDS total -> 2 blocks/CU.

#define BLOCK 1024
#define NBLOCKS 512
#define ITERS 16            // 128 points per block-iter; 512*16*128 = 1048576
#define STAGED_ROWS 16382   // levels 0..12: sum 2^(l+1) = 2^14-2
#define TBL_LDS_BYTES 65536
#define LDS_BYTES (TBL_LDS_BYTES + 16 * 128 * 8)   // +16KB transpose = 81920

__device__ __forceinline__ float2 ldsRow(const unsigned* lds, unsigned idx) {
    unsigned u = lds[idx];
    __half2 h = *(__half2*)&u;
    return __half22float2(h);
}

// Corner hash sums (h000 + D[c]) and trilinear weights, inline (SROA-safe).
#define PREP(FRES, HARR, WARR) \
    unsigned HARR[8]; float WARR[8]; { \
        const float csx = (px + 1.0f) * (FRES); \
        const float csy = (py + 1.0f) * (FRES); \
        const float csz = (pz + 1.0f) * (FRES); \
        const float cfx = floorf(csx), cfy = floorf(csy), cfz = floorf(csz); \
        const float tx = csx - cfx, ty = csy - cfy, tz = csz - cfz; \
        const unsigned hh = (unsigned)cfx * HA + (unsigned)cfy * HB + (unsigned)cfz * HC; \
        const float ux = 1.0f - tx, uy = 1.0f - ty, uz = 1.0f - tz; \
        WARR[0] = ux*uy*uz; WARR[1] = tx*uy*uz; WARR[2] = ux*ty*uz; WARR[3] = tx*ty*uz; \
        WARR[4] = ux*uy*tz; WARR[5] = tx*uy*tz; WARR[6] = ux*ty*tz; WARR[7] = tx*ty*tz; \
        HARR[0] = hh;           HARR[1] = hh + HA;           \
        HARR[2] = hh + HB;      HARR[3] = hh + HA + HB;      \
        HARR[4] = hh + HC;      HARR[5] = hh + HA + HC;      \
        HARR[6] = hh + HB + HC; HARR[7] = hh + HA + HB + HC; \
    }

#define GATHER_LDS(HARR, WARR, MASK, OFF, O0, O1) \
    { _Pragma("unroll") for (int c = 0; c < 8; ++c) { \
        float2 f = ldsRow(lds_tb, (OFF) + ((HARR[c]) & (MASK))); \
        (O0) += f.x * WARR[c]; (O1) += f.y * WARR[c]; } }

#define GATHER_GBL(HARR, WARR, MASK, OFF, O0, O1) \
    { _Pragma("unroll") for (int c = 0; c < 8; ++c) { \
        float2 f = tb[(OFF) + ((HARR[c]) & (MASK))]; \
        (O0) += f.x * WARR[c]; (O1) += f.y * WARR[c]; } }

__global__ __launch_bounds__(BLOCK) void ngp_encode_kernel(
    const float* __restrict__ coords,
    const float* __restrict__ table,
    float* __restrict__ out)
{
    extern __shared__ unsigned char lds_raw[];
    unsigned* lds_tb = (unsigned*)lds_raw;                   // 16382 half2 rows
    float2* lds_t = (float2*)(lds_raw + TBL_LDS_BYTES);      // [16][128], swizzled

    // ---- stage levels 0..12 as fp16 (float4 = 2 rows) ----
    {
        const float4* __restrict__ t4 = (const float4*)table;
        uint2* __restrict__ l2 = (uint2*)lds_tb;
        for (int r = threadIdx.x; r < STAGED_ROWS / 2; r += BLOCK) {  // 8191
            float4 v = t4[r];
            __half2 a = __floats2half2_rn(v.x, v.y);
            __half2 b = __floats2half2_rn(v.z, v.w);
            uint2 u;
            u.x = *(unsigned*)&a;
            u.y = *(unsigned*)&b;
            l2[r] = u;
        }
    }
    __syncthreads();

    constexpr unsigned P1 = 2654435761u, P2 = 29675113u, P3 = 123456789u;
    constexpr unsigned HA = P1 * P2 * P3;
    constexpr unsigned HB = P2 * P3;
    constexpr unsigned HC = P3;

    const float2* __restrict__ tb = (const float2*)table;
    float4* __restrict__ out4 = (float4*)out;

    // Wave-uniform level assignment: wave q owns levels lA=q (cheap) and
    // lB=15-q (expensive). Global path only for lB in {13,14,15} (q<3).
    const int wv   = __builtin_amdgcn_readfirstlane((int)(threadIdx.x >> 6));
    const int q    = wv & 7;
    const int g    = wv >> 3;           // point-group 0/1
    const int lane = threadIdx.x & 63;
    const int pl   = g * 64 + lane;     // local point 0..127

    const int lA = q;
    const int lB = 15 - q;
    const unsigned maskA = (2u << lA) - 1u, offA = maskA - 1u;
    const unsigned maskB = (2u << lB) - 1u, offB = maskB - 1u;

    for (int it = 0; it < ITERS; ++it) {
        const int pbase = blockIdx.x * (ITERS * 128) + it * 128;
        const int p = pbase + pl;

        const float px = coords[3 * p + 0];
        const float py = coords[3 * p + 1];
        const float pz = coords[3 * p + 2];

        float oA0 = 0.0f, oA1 = 0.0f, oB0 = 0.0f, oB1 = 0.0f;

        if (q < 3) {
            // lB in {15,14,13}: global (1MB table, L2-resident). Issue first
            // so the gather latency overlaps the LDS work below.
            {
                PREP(512.0f, hB, wB)
                GATHER_GBL(hB, wB, maskB, offB, oB0, oB1)
            }
            {
                const float fresA = (float)(16 << lA);
                PREP(fresA, hA, wA)
                GATHER_LDS(hA, wA, maskA, offA, oA0, oA1)
            }
        } else if (q < 5) {
            // lA in {3,4} (res<512) + lB in {12,11} LDS: two preps.
            {
                const float fresA = (float)(16 << lA);
                PREP(fresA, hA, wA)
                GATHER_LDS(hA, wA, maskA, offA, oA0, oA1)
            }
            {
                PREP(512.0f, hB, wB)
                GATHER_LDS(hB, wB, maskB, offB, oB0, oB1)
            }
        } else {
            // q=5,6,7: levels (5,10),(6,9),(7,8) -- all res 512, one prep.
            PREP(512.0f, hc, wc)
            GATHER_LDS(hc, wc, maskA, offA, oA0, oA1)
            GATHER_LDS(hc, wc, maskB, offB, oB0, oB1)
        }

        // ---- transpose through LDS: level-major [16][128] float2,
        // index XOR pl^(l&14) -> writes permuted-contiguous 512B/wave,
        // reads land 4 lanes per bank-pair (both bandwidth-optimal).
        lds_t[lA * 128 + (pl ^ (lA & 14))] = make_float2(oA0, oA1);
        lds_t[lB * 128 + (pl ^ (lB & 14))] = make_float2(oB0, oB1);
        __syncthreads();
        {
            const int j  = threadIdx.x;
            const int lp = j >> 3, qq = j & 7;
            float2 a = lds_t[(2 * qq + 0) * 128 + (lp ^ (2 * qq))];
            float2 b = lds_t[(2 * qq + 1) * 128 + (lp ^ (2 * qq))];
            out4[(size_t)pbase * 8 + j] = make_float4(a.x, a.y, b.x, b.y);
        }
        __syncthreads();
    }
}

extern "C" void kernel_launch(void* const* d_in, const int* in_sizes, int n_in,
                              void* d_out, int out_size, void* d_ws, size_t ws_size,
                              hipStream_t stream) {
    const float* coords = (const float*)d_in[0];
    const float* table  = (const float*)d_in[1];
    float* out = (float*)d_out;

    hipFuncSetAttribute((const void*)ngp_encode_kernel,
                        hipFuncAttributeMaxDynamicSharedMemorySize,
                        LDS_BYTES);

    ngp_encode_kernel<<<NBLOCKS, BLOCK, LDS_BYTES, stream>>>(coords, table, out);
}